// Round 6
// baseline (1833.903 us; speedup 1.0000x reference)
//
#include <hip/hip_runtime.h>

// Problem constants (Summarizer GConvGRU)
#define BB 8
#define TT 20
#define NV 10000
#define FF 9
#define EE 160000
#define BTT (BB*TT)      // 160
#define NROWS (BB*NV)    // 80000
#define NNZ (EE+NV)      // 170000
#define RPW 40           // rows per wave
#define NWAVES (NROWS/RPW)   // 2000
#define WPB 4                // waves per block (256 threads)
#define NBLK (NWAVES/WPB)    // 500

static __device__ __forceinline__ float fsig(float x){
  float e = __expf(-x);
  return __fdividef(1.0f, 1.0f + e);
}
static __device__ __forceinline__ float ftanh(float x){
  float e = __expf(-2.0f*x);
  float r = __fdividef(1.0f, 1.0f + e);
  return fmaf(-2.0f*e, r, 1.0f);
}
static __device__ __forceinline__ float rlane(float v, int k){
  return __int_as_float(__builtin_amdgcn_readlane(__float_as_int(v), k));
}

// 64-way textual repetition — straight-line code, compile-time indices
// everywhere (rule #20: no runtime-indexed register arrays).
#define REP64(M) \
  M(0)  M(1)  M(2)  M(3)  M(4)  M(5)  M(6)  M(7)  \
  M(8)  M(9)  M(10) M(11) M(12) M(13) M(14) M(15) \
  M(16) M(17) M(18) M(19) M(20) M(21) M(22) M(23) \
  M(24) M(25) M(26) M(27) M(28) M(29) M(30) M(31) \
  M(32) M(33) M(34) M(35) M(36) M(37) M(38) M(39) \
  M(40) M(41) M(42) M(43) M(44) M(45) M(46) M(47) \
  M(48) M(49) M(50) M(51) M(52) M(53) M(54) M(55) \
  M(56) M(57) M(58) M(59) M(60) M(61) M(62) M(63)

// ---------------- preprocessing kernels ----------------

__global__ void k_init_count(int* count){
  int n = blockIdx.x*256 + threadIdx.x;
  if (n < NV) count[n] = 1;               // self-loop
}

__global__ void k_count(const int* __restrict__ ei, int* count){
  int e = blockIdx.x*256 + threadIdx.x;
  if (e < EE) atomicAdd(&count[ei[EE + e]], 1);   // dst row
}

__global__ void k_scan(const int* __restrict__ count, int* __restrict__ row_ptr,
                       int* __restrict__ cursor){
  __shared__ int part[1024];
  int tid = threadIdx.x;
  int beg = tid*10;
  int s = 0;
  for (int i=0;i<10;i++){ int idx=beg+i; if (idx<NV) s += count[idx]; }
  part[tid]=s; __syncthreads();
  for (int off=1; off<1024; off<<=1){
    int v = (tid>=off) ? part[tid-off] : 0;
    __syncthreads();
    part[tid] += v;
    __syncthreads();
  }
  int run = (tid>0) ? part[tid-1] : 0;
  for (int i=0;i<10;i++){
    int idx=beg+i;
    if (idx<NV){ row_ptr[idx]=run; cursor[idx]=run+1; run += count[idx]; }
  }
  if (tid==1023) row_ptr[NV] = part[1023];
}

__global__ void k_dinv(const int* __restrict__ count, float* __restrict__ dinv){
  int n = blockIdx.x*256 + threadIdx.x;
  if (n < NV) dinv[n] = rsqrtf((float)count[n]);
}

__global__ void k_self(const int* __restrict__ row_ptr, const float* __restrict__ dinv,
                       int* __restrict__ csr_src, float* __restrict__ csr_w){
  int n = blockIdx.x*256 + threadIdx.x;
  if (n < NV){
    int p = row_ptr[n];
    csr_src[p] = n;
    csr_w[p] = dinv[n]*dinv[n];
  }
}

__global__ void k_scatter(const int* __restrict__ ei, const float* __restrict__ dinv,
                          int* cursor, int* __restrict__ csr_src, float* __restrict__ csr_w){
  int e = blockIdx.x*256 + threadIdx.x;
  if (e < EE){
    int s = ei[e];
    int d = ei[EE + e];
    int p = atomicAdd(&cursor[d], 1);
    csr_src[p] = s;
    csr_w[p] = dinv[s]*dinv[d];
  }
}

// u_g = Wc_g @ Wl_g[:64], c_g = bc_g @ Wl_g[:64] + bl_g   (uc layout: g*128 + {0:u, 64:c})
__global__ void k_uc(const float* Wcz,const float* bcz,const float* Wlz,const float* blz,
                     const float* Wcr,const float* bcr,const float* Wlr,const float* blr,
                     const float* Wch,const float* bch,const float* Wlh,const float* blh,
                     float* uc){
  int tid = threadIdx.x;           // 192
  int g = tid>>6, h = tid&63;
  const float* Wc = (g==0)?Wcz:(g==1)?Wcr:Wch;
  const float* bc = (g==0)?bcz:(g==1)?bcr:bch;
  const float* Wl = (g==0)?Wlz:(g==1)?Wlr:Wlh;
  const float* bl = (g==0)?blz:(g==1)?blr:blh;
  float u=0.f, c=0.f;
  for (int k=0;k<64;++k){
    float wl = Wl[k*64 + h];
    u = fmaf(Wc[k], wl, u);
    c = fmaf(bc[k], wl, c);
  }
  uc[g*128 + h]      = u;
  uc[g*128 + 64 + h] = c + bl[h];
}

// extract x_rec transposed: xrT[n][bt], via LDS tile so each xrT line is
// written once, coalesced, by one block (kills cross-XCD RFO ping-pong).
#define TN 64
__global__ __launch_bounds__(256) void k_extract(const float* __restrict__ obs,
                                                 float* __restrict__ xrT){
  __shared__ float tile[BTT][TN+1];   // 160 x 65 x 4B = 41.6 KB
  const int n0  = blockIdx.x * TN;
  const int tid = threadIdx.x;
  const int j   = tid & 63;       // vertex offset within tile
  const int w   = tid >> 6;       // wave id 0..3
  if (n0 + j < NV){
    for (int c = 0; c < BTT/4; ++c){
      int bt = c*4 + w;
      tile[bt][j] = obs[((size_t)bt*NV + n0 + j)*FF + 8];
    }
  }
  __syncthreads();
  float* dst = xrT + (size_t)n0*BTT;
  for (int o = tid; o < TN*BTT; o += 256){
    int n = o / BTT, bt = o - n*BTT;
    if (n0 + n < NV) dst[o] = tile[bt][n];
  }
}

// S[bt][n] = sum over incoming edges (incl self loop) of w * xrT[src][bt]
__global__ void k_spmv(const float* __restrict__ xrT, const int* __restrict__ row_ptr,
                       const int* __restrict__ csr_src, const float* __restrict__ csr_w,
                       float* __restrict__ S){
  int n = blockIdx.x;
  int lane = threadIdx.x;          // 64
  int e0 = row_ptr[n], e1 = row_ptr[n+1];
  float a0=0.f, a1=0.f, a2=0.f;
  for (int e=e0; e<e1; ++e){
    int s = csr_src[e];
    float w = csr_w[e];
    const float* xr = xrT + (size_t)s*BTT;
    a0 = fmaf(w, xr[lane],      a0);
    a1 = fmaf(w, xr[64 + lane], a1);
    if (lane < 32) a2 = fmaf(w, xr[128 + lane], a2);
  }
  S[(size_t)lane*NV + n]        = a0;
  S[(size_t)(64+lane)*NV + n]   = a1;
  if (lane < 32) S[(size_t)(128+lane)*NV + n] = a2;
}

// ---------------- GRU recurrence ----------------
// lane = output column h; wave = 40 rows x 20 timesteps. Weights as 192 NAMED
// scalars (macro-generated straight-line body) so the compiler MUST hold them
// in arch VGPRs — R5 showed the array form spilled (VGPR_Count=112 < 192).

#define DECLW(k) float vz##k, vr##k, vh##k;
#define LOADW(k) vz##k = Wlz[(64+(k))*64+lane]; \
                 vr##k = Wlr[(64+(k))*64+lane]; \
                 vh##k = Wlh[(64+(k))*64+lane];
#define ZR(k) { float h_ = rlane(hvec, k); \
                if ((k)&1){ az1 = fmaf(h_, vz##k, az1); ar1 = fmaf(h_, vr##k, ar1); } \
                else      { az0 = fmaf(h_, vz##k, az0); ar0 = fmaf(h_, vr##k, ar0); } }
#define HS(k) { float g_ = rlane(hr, k); \
                if ((k)&1) ah1 = fmaf(g_, vh##k, ah1); \
                else       ah0 = fmaf(g_, vh##k, ah0); }

__global__ __launch_bounds__(256, 2) void k_gru(
    const float* __restrict__ S, const float* __restrict__ obs,
    const float* __restrict__ Wlz, const float* __restrict__ Wlr,
    const float* __restrict__ Wlh, const float* __restrict__ uc,
    float* __restrict__ out)
{
  __shared__ float Hs[WPB][RPW*64];    // 40 KB/block, wave-private regions
  const int tid  = threadIdx.x;
  const int w    = tid >> 6;
  const int lane = tid & 63;
  const int W    = blockIdx.x*WPB + w;       // [0, 2000)
  const int row0 = W * RPW;
  const int b    = row0 / NV;                // 40 | 10000 -> whole wave in one b
  const int n0   = row0 - b*NV;

  REP64(DECLW)
  REP64(LOADW)

  const float uz = uc[lane],     cz = uc[64+lane];
  const float ur = uc[128+lane], cr = uc[192+lane];
  const float uh = uc[256+lane], ch = uc[320+lane];

  float* hbase = &Hs[w][0];
  for (int m=0;m<RPW;++m) hbase[m*64+lane] = 0.0f;

  float sv = (lane < RPW) ? S[(size_t)(b*TT)*NV + n0 + lane] : 0.0f;

  for (int t=0; t<TT; ++t){
    float sv_next = 0.0f;
    if (t+1 < TT && lane < RPW)
      sv_next = S[(size_t)(b*TT + t + 1)*NV + n0 + lane];
    const float* obsrow = obs + ((size_t)(b*TT+t)*NV + n0)*FF;
    float*       outrow = out + ((size_t)(b*TT+t)*NV + n0)*72;

    #pragma unroll 1
    for (int m=0; m<RPW; ++m){
      float s = rlane(sv, m);
      float xo = 0.0f;
      if (lane < 8) xo = obsrow[(size_t)m*FF + lane];
      float hvec = hbase[m*64 + lane];

      float az0 = fmaf(s, uz, cz), az1 = 0.0f;
      float ar0 = fmaf(s, ur, cr), ar1 = 0.0f;
      REP64(ZR)
      float z = fsig(az0 + az1);
      float r = fsig(ar0 + ar1);
      float hr = hvec * r;

      float ah0 = fmaf(s, uh, ch), ah1 = 0.0f;
      REP64(HS)
      float htil = ftanh(ah0 + ah1);
      float hn = fmaf(z, hvec - htil, htil);

      hbase[m*64 + lane] = hn;
      outrow[(size_t)m*72 + 8 + lane] = hn;
      if (lane < 8) outrow[(size_t)m*72 + lane] = xo;
    }
    sv = sv_next;
  }
}

// ---------------- launcher ----------------

extern "C" void kernel_launch(void* const* d_in, const int* in_sizes, int n_in,
                              void* d_out, int out_size, void* d_ws, size_t ws_size,
                              hipStream_t stream) {
  const float* obs  = (const float*)d_in[0];
  const int*   ei   = (const int*)d_in[1];
  const float* Wcz = (const float*)d_in[2];  const float* bcz = (const float*)d_in[3];
  const float* Wlz = (const float*)d_in[4];  const float* blz = (const float*)d_in[5];
  const float* Wcr = (const float*)d_in[6];  const float* bcr = (const float*)d_in[7];
  const float* Wlr = (const float*)d_in[8];  const float* blr = (const float*)d_in[9];
  const float* Wch = (const float*)d_in[10]; const float* bch = (const float*)d_in[11];
  const float* Wlh = (const float*)d_in[12]; const float* blh = (const float*)d_in[13];
  float* out = (float*)d_out;

  char* w = (char*)d_ws;
  size_t off = 0;
  auto alloc = [&](size_t bytes) -> void* {
    void* p = w + off;
    off = (off + bytes + 255) & ~(size_t)255;
    return p;
  };
  float* xrT     = (float*)alloc((size_t)NV*BTT*4);
  float* S       = (float*)alloc((size_t)BTT*NV*4);
  int*   count   = (int*)  alloc((size_t)NV*4);
  int*   row_ptr = (int*)  alloc((size_t)(NV+1)*4);
  int*   cursor  = (int*)  alloc((size_t)NV*4);
  float* dinv    = (float*)alloc((size_t)NV*4);
  int*   csr_src = (int*)  alloc((size_t)NNZ*4);
  float* csr_w   = (float*)alloc((size_t)NNZ*4);
  float* uc      = (float*)alloc(384*4);

  hipLaunchKernelGGL(k_init_count, dim3((NV+255)/256), dim3(256), 0, stream, count);
  hipLaunchKernelGGL(k_count,      dim3((EE+255)/256), dim3(256), 0, stream, ei, count);
  hipLaunchKernelGGL(k_scan,       dim3(1), dim3(1024), 0, stream, count, row_ptr, cursor);
  hipLaunchKernelGGL(k_dinv,       dim3((NV+255)/256), dim3(256), 0, stream, count, dinv);
  hipLaunchKernelGGL(k_self,       dim3((NV+255)/256), dim3(256), 0, stream, row_ptr, dinv, csr_src, csr_w);
  hipLaunchKernelGGL(k_scatter,    dim3((EE+255)/256), dim3(256), 0, stream, ei, dinv, cursor, csr_src, csr_w);
  hipLaunchKernelGGL(k_uc,         dim3(1), dim3(192), 0, stream,
                     Wcz,bcz,Wlz,blz, Wcr,bcr,Wlr,blr, Wch,bch,Wlh,blh, uc);
  hipLaunchKernelGGL(k_extract,    dim3((NV+TN-1)/TN), dim3(256), 0, stream, obs, xrT);
  hipLaunchKernelGGL(k_spmv,       dim3(NV), dim3(64), 0, stream, xrT, row_ptr, csr_src, csr_w, S);
  hipLaunchKernelGGL(k_gru,        dim3(NBLK), dim3(256), 0, stream, S, obs, Wlz, Wlr, Wlh, uc, out);
}

// Round 7
// 1833.448 us; speedup vs baseline: 1.0002x; 1.0002x over previous
//
#include <hip/hip_runtime.h>

// Problem constants (Summarizer GConvGRU)
#define BB 8
#define TT 20
#define NV 10000
#define FF 9
#define EE 160000
#define BTT (BB*TT)      // 160
#define NROWS (BB*NV)    // 80000
#define NNZ (EE+NV)      // 170000
#define RPW 40           // rows per wave
#define NWAVES (NROWS/RPW)   // 2000
#define WPB 4                // waves per block (256 threads)
#define NBLK (NWAVES/WPB)    // 500

static __device__ __forceinline__ float fsig(float x){
  float e = __expf(-x);
  return __fdividef(1.0f, 1.0f + e);
}
static __device__ __forceinline__ float ftanh(float x){
  float e = __expf(-2.0f*x);
  float r = __fdividef(1.0f, 1.0f + e);
  return fmaf(-2.0f*e, r, 1.0f);
}
static __device__ __forceinline__ float rlane(float v, int k){
  return __int_as_float(__builtin_amdgcn_readlane(__float_as_int(v), k));
}

// 64-way textual repetition — straight-line code, compile-time indices.
#define REP64(M) \
  M(0)  M(1)  M(2)  M(3)  M(4)  M(5)  M(6)  M(7)  \
  M(8)  M(9)  M(10) M(11) M(12) M(13) M(14) M(15) \
  M(16) M(17) M(18) M(19) M(20) M(21) M(22) M(23) \
  M(24) M(25) M(26) M(27) M(28) M(29) M(30) M(31) \
  M(32) M(33) M(34) M(35) M(36) M(37) M(38) M(39) \
  M(40) M(41) M(42) M(43) M(44) M(45) M(46) M(47) \
  M(48) M(49) M(50) M(51) M(52) M(53) M(54) M(55) \
  M(56) M(57) M(58) M(59) M(60) M(61) M(62) M(63)

// ---------------- preprocessing kernels ----------------

__global__ void k_init_count(int* count){
  int n = blockIdx.x*256 + threadIdx.x;
  if (n < NV) count[n] = 1;               // self-loop
}

__global__ void k_count(const int* __restrict__ ei, int* count){
  int e = blockIdx.x*256 + threadIdx.x;
  if (e < EE) atomicAdd(&count[ei[EE + e]], 1);   // dst row
}

__global__ void k_scan(const int* __restrict__ count, int* __restrict__ row_ptr,
                       int* __restrict__ cursor){
  __shared__ int part[1024];
  int tid = threadIdx.x;
  int beg = tid*10;
  int s = 0;
  for (int i=0;i<10;i++){ int idx=beg+i; if (idx<NV) s += count[idx]; }
  part[tid]=s; __syncthreads();
  for (int off=1; off<1024; off<<=1){
    int v = (tid>=off) ? part[tid-off] : 0;
    __syncthreads();
    part[tid] += v;
    __syncthreads();
  }
  int run = (tid>0) ? part[tid-1] : 0;
  for (int i=0;i<10;i++){
    int idx=beg+i;
    if (idx<NV){ row_ptr[idx]=run; cursor[idx]=run+1; run += count[idx]; }
  }
  if (tid==1023) row_ptr[NV] = part[1023];
}

__global__ void k_dinv(const int* __restrict__ count, float* __restrict__ dinv){
  int n = blockIdx.x*256 + threadIdx.x;
  if (n < NV) dinv[n] = rsqrtf((float)count[n]);
}

__global__ void k_self(const int* __restrict__ row_ptr, const float* __restrict__ dinv,
                       int* __restrict__ csr_src, float* __restrict__ csr_w){
  int n = blockIdx.x*256 + threadIdx.x;
  if (n < NV){
    int p = row_ptr[n];
    csr_src[p] = n;
    csr_w[p] = dinv[n]*dinv[n];
  }
}

__global__ void k_scatter(const int* __restrict__ ei, const float* __restrict__ dinv,
                          int* cursor, int* __restrict__ csr_src, float* __restrict__ csr_w){
  int e = blockIdx.x*256 + threadIdx.x;
  if (e < EE){
    int s = ei[e];
    int d = ei[EE + e];
    int p = atomicAdd(&cursor[d], 1);
    csr_src[p] = s;
    csr_w[p] = dinv[s]*dinv[d];
  }
}

// u_g = Wc_g @ Wl_g[:64], c_g = bc_g @ Wl_g[:64] + bl_g   (uc layout: g*128 + {0:u, 64:c})
__global__ void k_uc(const float* Wcz,const float* bcz,const float* Wlz,const float* blz,
                     const float* Wcr,const float* bcr,const float* Wlr,const float* blr,
                     const float* Wch,const float* bch,const float* Wlh,const float* blh,
                     float* uc){
  int tid = threadIdx.x;           // 192
  int g = tid>>6, h = tid&63;
  const float* Wc = (g==0)?Wcz:(g==1)?Wcr:Wch;
  const float* bc = (g==0)?bcz:(g==1)?bcr:bch;
  const float* Wl = (g==0)?Wlz:(g==1)?Wlr:Wlh;
  const float* bl = (g==0)?blz:(g==1)?blr:blh;
  float u=0.f, c=0.f;
  for (int k=0;k<64;++k){
    float wl = Wl[k*64 + h];
    u = fmaf(Wc[k], wl, u);
    c = fmaf(bc[k], wl, c);
  }
  uc[g*128 + h]      = u;
  uc[g*128 + 64 + h] = c + bl[h];
}

// extract x_rec transposed: xrT[n][bt], via LDS tile (one coalesced write
// per xrT line, no cross-XCD RFO ping-pong).
#define TN 64
__global__ __launch_bounds__(256) void k_extract(const float* __restrict__ obs,
                                                 float* __restrict__ xrT){
  __shared__ float tile[BTT][TN+1];   // 160 x 65 x 4B = 41.6 KB
  const int n0  = blockIdx.x * TN;
  const int tid = threadIdx.x;
  const int j   = tid & 63;
  const int w   = tid >> 6;
  if (n0 + j < NV){
    for (int c = 0; c < BTT/4; ++c){
      int bt = c*4 + w;
      tile[bt][j] = obs[((size_t)bt*NV + n0 + j)*FF + 8];
    }
  }
  __syncthreads();
  float* dst = xrT + (size_t)n0*BTT;
  for (int o = tid; o < TN*BTT; o += 256){
    int n = o / BTT, bt = o - n*BTT;
    if (n0 + n < NV) dst[o] = tile[bt][n];
  }
}

// S[bt][n] = sum over incoming edges (incl self loop) of w * xrT[src][bt]
__global__ void k_spmv(const float* __restrict__ xrT, const int* __restrict__ row_ptr,
                       const int* __restrict__ csr_src, const float* __restrict__ csr_w,
                       float* __restrict__ S){
  int n = blockIdx.x;
  int lane = threadIdx.x;          // 64
  int e0 = row_ptr[n], e1 = row_ptr[n+1];
  float a0=0.f, a1=0.f, a2=0.f;
  for (int e=e0; e<e1; ++e){
    int s = csr_src[e];
    float w = csr_w[e];
    const float* xr = xrT + (size_t)s*BTT;
    a0 = fmaf(w, xr[lane],      a0);
    a1 = fmaf(w, xr[64 + lane], a1);
    if (lane < 32) a2 = fmaf(w, xr[128 + lane], a2);
  }
  S[(size_t)lane*NV + n]        = a0;
  S[(size_t)(64+lane)*NV + n]   = a1;
  if (lane < 32) S[(size_t)(128+lane)*NV + n] = a2;
}

// ---------------- GRU recurrence ----------------
// lane = output column h; wave = 40 rows x 20 timesteps.
// R5/R6 lesson: the 192 weight loads are loop-invariant restrict-loads, so
// LLVM remats them (reload from L2 per use) instead of keeping them in VGPRs
// (VGPR_Count stuck at 112). Fix: pass every weight through asm volatile
// "+v" pins — opaque defs can't be rematerialized, forcing VGPR residency.

#define DECLW(k) float vz##k, vr##k, vh##k;
#define LOADW(k) vz##k = Wlz[(64+(k))*64+lane]; \
                 vr##k = Wlr[(64+(k))*64+lane]; \
                 vh##k = Wlh[(64+(k))*64+lane];
#define PINW(k)  asm volatile("" : "+v"(vz##k), "+v"(vr##k), "+v"(vh##k));
#define ZR(k) { float h_ = rlane(hvec, k); \
                if ((k)&1){ az1 = fmaf(h_, vz##k, az1); ar1 = fmaf(h_, vr##k, ar1); } \
                else      { az0 = fmaf(h_, vz##k, az0); ar0 = fmaf(h_, vr##k, ar0); } }
#define HS(k) { float g_ = rlane(hr, k); \
                if ((k)&1) ah1 = fmaf(g_, vh##k, ah1); \
                else       ah0 = fmaf(g_, vh##k, ah0); }

__global__ __launch_bounds__(256, 2) void k_gru(
    const float* __restrict__ S, const float* __restrict__ obs,
    const float* __restrict__ Wlz, const float* __restrict__ Wlr,
    const float* __restrict__ Wlh, const float* __restrict__ uc,
    float* __restrict__ out)
{
  __shared__ float Hs[WPB][RPW*64];    // 40 KB/block, wave-private regions
  const int tid  = threadIdx.x;
  const int w    = tid >> 6;
  const int lane = tid & 63;
  const int W    = blockIdx.x*WPB + w;       // [0, 2000)
  const int row0 = W * RPW;
  const int b    = row0 / NV;                // 40 | 10000 -> whole wave in one b
  const int n0   = row0 - b*NV;

  REP64(DECLW)
  REP64(LOADW)
  REP64(PINW)      // defeat remat: weights now defined by opaque asm

  const float uz = uc[lane],     cz = uc[64+lane];
  const float ur = uc[128+lane], cr = uc[192+lane];
  const float uh = uc[256+lane], ch = uc[320+lane];

  float* hbase = &Hs[w][0];
  for (int m=0;m<RPW;++m) hbase[m*64+lane] = 0.0f;

  float sv = (lane < RPW) ? S[(size_t)(b*TT)*NV + n0 + lane] : 0.0f;

  for (int t=0; t<TT; ++t){
    REP64(PINW)    // loop-carried through opaque asm -> must stay resident

    float sv_next = 0.0f;
    if (t+1 < TT && lane < RPW)
      sv_next = S[(size_t)(b*TT + t + 1)*NV + n0 + lane];
    const float* obsrow = obs + ((size_t)(b*TT+t)*NV + n0)*FF;
    float*       outrow = out + ((size_t)(b*TT+t)*NV + n0)*72;

    #pragma unroll 1
    for (int m=0; m<RPW; ++m){
      float s = rlane(sv, m);
      float xo = 0.0f;
      if (lane < 8) xo = obsrow[(size_t)m*FF + lane];
      float hvec = hbase[m*64 + lane];

      float az0 = fmaf(s, uz, cz), az1 = 0.0f;
      float ar0 = fmaf(s, ur, cr), ar1 = 0.0f;
      REP64(ZR)
      float z = fsig(az0 + az1);
      float r = fsig(ar0 + ar1);
      float hr = hvec * r;

      float ah0 = fmaf(s, uh, ch), ah1 = 0.0f;
      REP64(HS)
      float htil = ftanh(ah0 + ah1);
      float hn = fmaf(z, hvec - htil, htil);

      hbase[m*64 + lane] = hn;
      outrow[(size_t)m*72 + 8 + lane] = hn;
      if (lane < 8) outrow[(size_t)m*72 + lane] = xo;
    }
    sv = sv_next;
  }
}

// ---------------- launcher ----------------

extern "C" void kernel_launch(void* const* d_in, const int* in_sizes, int n_in,
                              void* d_out, int out_size, void* d_ws, size_t ws_size,
                              hipStream_t stream) {
  const float* obs  = (const float*)d_in[0];
  const int*   ei   = (const int*)d_in[1];
  const float* Wcz = (const float*)d_in[2];  const float* bcz = (const float*)d_in[3];
  const float* Wlz = (const float*)d_in[4];  const float* blz = (const float*)d_in[5];
  const float* Wcr = (const float*)d_in[6];  const float* bcr = (const float*)d_in[7];
  const float* Wlr = (const float*)d_in[8];  const float* blr = (const float*)d_in[9];
  const float* Wch = (const float*)d_in[10]; const float* bch = (const float*)d_in[11];
  const float* Wlh = (const float*)d_in[12]; const float* blh = (const float*)d_in[13];
  float* out = (float*)d_out;

  char* w = (char*)d_ws;
  size_t off = 0;
  auto alloc = [&](size_t bytes) -> void* {
    void* p = w + off;
    off = (off + bytes + 255) & ~(size_t)255;
    return p;
  };
  float* xrT     = (float*)alloc((size_t)NV*BTT*4);
  float* S       = (float*)alloc((size_t)BTT*NV*4);
  int*   count   = (int*)  alloc((size_t)NV*4);
  int*   row_ptr = (int*)  alloc((size_t)(NV+1)*4);
  int*   cursor  = (int*)  alloc((size_t)NV*4);
  float* dinv    = (float*)alloc((size_t)NV*4);
  int*   csr_src = (int*)  alloc((size_t)NNZ*4);
  float* csr_w   = (float*)alloc((size_t)NNZ*4);
  float* uc      = (float*)alloc(384*4);

  hipLaunchKernelGGL(k_init_count, dim3((NV+255)/256), dim3(256), 0, stream, count);
  hipLaunchKernelGGL(k_count,      dim3((EE+255)/256), dim3(256), 0, stream, ei, count);
  hipLaunchKernelGGL(k_scan,       dim3(1), dim3(1024), 0, stream, count, row_ptr, cursor);
  hipLaunchKernelGGL(k_dinv,       dim3((NV+255)/256), dim3(256), 0, stream, count, dinv);
  hipLaunchKernelGGL(k_self,       dim3((NV+255)/256), dim3(256), 0, stream, row_ptr, dinv, csr_src, csr_w);
  hipLaunchKernelGGL(k_scatter,    dim3((EE+255)/256), dim3(256), 0, stream, ei, dinv, cursor, csr_src, csr_w);
  hipLaunchKernelGGL(k_uc,         dim3(1), dim3(192), 0, stream,
                     Wcz,bcz,Wlz,blz, Wcr,bcr,Wlr,blr, Wch,bch,Wlh,blh, uc);
  hipLaunchKernelGGL(k_extract,    dim3((NV+TN-1)/TN), dim3(256), 0, stream, obs, xrT);
  hipLaunchKernelGGL(k_spmv,       dim3(NV), dim3(64), 0, stream, xrT, row_ptr, csr_src, csr_w, S);
  hipLaunchKernelGGL(k_gru,        dim3(NBLK), dim3(256), 0, stream, S, obs, Wlz, Wlr, Wlh, uc, out);
}